// Round 20
// baseline (468.024 us; speedup 1.0000x reference)
//
#include <hip/hip_runtime.h>
#include <hip/hip_bf16.h>
#include <stdint.h>

// ---------------------------------------------------------------------------
// LoRALinear: y = x @ (W + B@A)^T + (b + lora_bias)
// M=8192, N=4096, K=4096.
// R20: B operands read DIRECTLY from global (L2-resident per R7 mapping)
// into registers, prefetched 1 phase early; only A staged through LDS.
//  - LDS traffic/KT 192->128 KB: phases (753+621)/(621)/(753+621)/(621)
//  - staging loads halve; ldsB freed (LDS 128->64 KB)
//  - zero extra regs: b01 dead after Q10 (reload at p4 for t+1);
//    b23 dead after Q11 (reload at p1 for t)
//  - vmcnt ledger: Q00 vmcnt(6) [q: b01:4,b23:4,sA:2]; Q01 vmcnt(4);
//    p4: issue b01(t+1) THEN vmcnt(4) drains exactly sA(t+1) -> publish BAR.
//    Tails: vmcnt(4)/(0) when issues skipped.
// R4/R11: ~250 reg cap (this stays ~245). R5: drain-then-barrier publication
// for A unchanged. R13/R19: phase time = LDS window + MFMA window, additive.
// ---------------------------------------------------------------------------

#define M_DIM 8192
#define N_DIM 4096
#define K_DIM 4096
#define NT    (K_DIM / 64)   // 64 K-tiles

typedef __attribute__((ext_vector_type(8))) short bf16x8;
typedef __attribute__((ext_vector_type(4))) float f32x4;

#define BARRIER() __builtin_amdgcn_s_barrier()
#define WAITV6() asm volatile("s_waitcnt vmcnt(6)" ::: "memory")
#define WAITV4() asm volatile("s_waitcnt vmcnt(4)" ::: "memory")
#define WAITV0() asm volatile("s_waitcnt vmcnt(0)" ::: "memory")
#define LGKM0()  asm volatile("s_waitcnt lgkmcnt(0)" ::: "memory")
#define MEMFENCE() asm volatile("" ::: "memory")

static __device__ __forceinline__ unsigned short f2bf(float f) {
    unsigned int u = __builtin_bit_cast(unsigned int, f);
    unsigned int r = (u + 0x7fffu + ((u >> 16) & 1u)) >> 16;
    return (unsigned short)r;
}

// --- merged pre-pass: blocks [0,8192) convert x -> bf16 (8 elems/thread);
//     blocks [8192,9216) compute bf16(W + B@A), 4 rows/block. -----------------
#define CONVX_BLOCKS 8192
__global__ __launch_bounds__(512) void conv_xw_kernel(
    const float* __restrict__ x, unsigned short* __restrict__ xb,
    const float* __restrict__ W, const float* __restrict__ lA,
    const float* __restrict__ lB, unsigned short* __restrict__ Wb) {
    const int bid = blockIdx.x;
    if (bid < CONVX_BLOCKS) {
        size_t i = ((size_t)bid * 512 + threadIdx.x) * 8;
        float4 a = *(const float4*)(x + i);
        float4 c = *(const float4*)(x + i + 4);
        union { unsigned short us[8]; uint4 v; } u;
        u.us[0] = f2bf(a.x); u.us[1] = f2bf(a.y); u.us[2] = f2bf(a.z); u.us[3] = f2bf(a.w);
        u.us[4] = f2bf(c.x); u.us[5] = f2bf(c.y); u.us[6] = f2bf(c.z); u.us[7] = f2bf(c.w);
        *(uint4*)(xb + i) = u.v;
        return;
    }
    const int nb = (bid - CONVX_BLOCKS) * 4;
    const int k0 = threadIdx.x * 8;       // 512 thr * 8 = 4096

    float acc[4][8];
#pragma unroll
    for (int r = 0; r < 4; ++r) {
        const float4* w4 = (const float4*)(W + (size_t)(nb + r) * K_DIM + k0);
        float4 v0 = w4[0], v1 = w4[1];
        acc[r][0] = v0.x; acc[r][1] = v0.y; acc[r][2] = v0.z; acc[r][3] = v0.w;
        acc[r][4] = v1.x; acc[r][5] = v1.y; acc[r][6] = v1.z; acc[r][7] = v1.w;
    }
    float brs[4][16];
#pragma unroll
    for (int r = 0; r < 4; ++r)
#pragma unroll
        for (int t = 0; t < 16; ++t) brs[r][t] = lB[(size_t)(nb + r) * 16 + t];

#pragma unroll
    for (int t = 0; t < 16; ++t) {
        const float4* a4 = (const float4*)(lA + (size_t)t * K_DIM + k0);
        float4 v0 = a4[0], v1 = a4[1];
        float av[8] = {v0.x, v0.y, v0.z, v0.w, v1.x, v1.y, v1.z, v1.w};
#pragma unroll
        for (int r = 0; r < 4; ++r)
#pragma unroll
            for (int j = 0; j < 8; ++j) acc[r][j] += brs[r][t] * av[j];
    }
#pragma unroll
    for (int r = 0; r < 4; ++r) {
        union { unsigned short us[8]; uint4 v; } u;
#pragma unroll
        for (int j = 0; j < 8; ++j) u.us[j] = f2bf(acc[r][j]);
        *(uint4*)(Wb + (size_t)(nb + r) * K_DIM + k0) = u.v;
    }
}

// --- gemm: 256x256 tile, BK=64, 8 waves; A via LDS, B direct-from-L2 --------
__global__ __launch_bounds__(512, 2) void gemm_kernel(
    const unsigned short* __restrict__ A,   // [8192][4096] bf16
    const unsigned short* __restrict__ B,   // [4096][4096] bf16 (W')
    const float* __restrict__ bvec, const float* __restrict__ lbvec,
    float* __restrict__ C) {
    const int tid = threadIdx.x;
    const int lane = tid & 63;
    const int wid = tid >> 6;        // 0..7
    const int wr = wid >> 2;         // 0..1  M-half (128 rows)
    const int wc = wid & 3;          // 0..3  N-quarter (64 cols)

    // XCD-column-resident mapping (R7): B panels L2-resident per XCD.
    const int bid = blockIdx.x;
    const int ntile = (bid & 7) * 2 + ((bid >> 3) & 1);  // 0..15
    const int mtile = bid >> 4;                          // 0..31
    const int m0 = mtile * 256, n0 = ntile * 256;

    __shared__ __align__(16) unsigned short ldsA[2 * 2 * 128 * 64];  // 64 KiB

    // --- A staging: linear LDS dest, inverse-swizzled global src (T2) ---
    const int lr8 = lane >> 3;             // 0..7
    const int cch = (lane & 7) ^ lr8;      // swizzled 16B-chunk index
    const unsigned short* aSb = A + (size_t)(m0 + lr8) * K_DIM + cch * 8;

    auto stageA = [&](int par_, int h, int kt) {   // one half-tile = 2 loads
#pragma unroll
        for (int s = 0; s < 2; ++s) {
            const int j = wid * 2 + s;
            const unsigned short* g = aSb + (size_t)(h * 128 + j * 8) * K_DIM + kt * 64;
            __builtin_amdgcn_global_load_lds(
                (const __attribute__((address_space(1))) void*)g,
                (__attribute__((address_space(3))) void*)(ldsA + (par_ * 2 + h) * 8192 + j * 512),
                16, 0, 0);
        }
    };

    // --- A read side (T2 swizzle) ---
    const int rowByte = (lane & 15) * 128;
    const int swz = (lane & 7) << 4;
    const int kc0 = (0 * 64 + (lane >> 4) * 16) ^ swz;
    const int kc1 = (1 * 64 + (lane >> 4) * 16) ^ swz;

    auto readA = [&](int par_, int mf, int kk) -> bf16x8 {
        const char* p = (const char*)(ldsA + (par_ * 2 + wr) * 8192 + mf * 1024) +
                        rowByte + (kk ? kc1 : kc0);
        return *(const bf16x8*)p;
    };

    // --- B direct-from-global fragments (same lane->element map as before):
    //     row = n0 + wc*64 + nf*16 + (lane&15); col = kt*64 + kk*32 + (lane>>4)*8
    const unsigned short* bF = B + (size_t)(n0 + wc * 64 + (lane & 15)) * K_DIM +
                               (lane >> 4) * 8;
    auto loadB = [&](int nf, int kk, int kt) -> bf16x8 {
        return *(const bf16x8*)(bF + (size_t)(nf * 16) * K_DIM + kt * 64 + kk * 32);
    };

    f32x4 acc[8][4] = {};
    bf16x8 a[4][2], b[4][2];

    auto mfmaQ = [&](int qm, int qn) {   // 16 MFMA: 4 mf x 2 nf x 2 kk
#pragma unroll
        for (int i = 0; i < 4; ++i)
#pragma unroll
            for (int jn = 0; jn < 2; ++jn)
#pragma unroll
                for (int kk = 0; kk < 2; ++kk)
                    acc[qm * 4 + i][qn * 2 + jn] = __builtin_amdgcn_mfma_f32_16x16x32_bf16(
                        a[i][kk], b[qn * 2 + jn][kk], acc[qm * 4 + i][qn * 2 + jn], 0, 0, 0);
    };

    // --- prologue: stage A(0) [4]; issue b01(0) [4]; drain A(0); publish ---
    stageA(0, 0, 0); stageA(0, 1, 0);
#pragma unroll
    for (int nf = 0; nf < 2; ++nf)
#pragma unroll
        for (int kk = 0; kk < 2; ++kk) b[nf][kk] = loadB(nf, kk, 0);
    MEMFENCE();
    WAITV4();               // A(0) drained; b01(0) in flight
    BARRIER();              // publish A(0)

    // Per K-tile:
    //  p1: issue b23(t); a03 ds-reads; stageA(t+1,h0); vmcnt(6) [b01(t)]; Q00
    //  p2: stageA(t+1,h1); vmcnt(4) [b23(t)]; Q01
    //  p3: a47 ds-reads; Q10
    //  p4: issue b01(t+1); vmcnt(4) [drains sA(t+1)]; publish BAR; Q11
#define KTILE(kt, par)                                                          \
    {                                                                           \
        /* p1 */                                                                \
        _Pragma("unroll") for (int nf = 2; nf < 4; ++nf)                        \
            _Pragma("unroll") for (int kk = 0; kk < 2; ++kk)                    \
                b[nf][kk] = loadB(nf, kk, kt);                                   \
        _Pragma("unroll") for (int i = 0; i < 4; ++i)                           \
            _Pragma("unroll") for (int kk = 0; kk < 2; ++kk)                    \
                a[i][kk] = readA(par, i, kk);                                    \
        if ((kt) + 1 < NT) stageA((par) ^ 1, 0, (kt) + 1);                      \
        MEMFENCE();                                                             \
        BARRIER();                                                              \
        LGKM0();                                                                \
        if ((kt) + 1 < NT) { WAITV6(); } else { WAITV4(); }                     \
        __builtin_amdgcn_s_setprio(1); mfmaQ(0, 0); __builtin_amdgcn_s_setprio(0); \
        BARRIER();                                                              \
        /* p2 */                                                                \
        if ((kt) + 1 < NT) stageA((par) ^ 1, 1, (kt) + 1);                      \
        MEMFENCE();                                                             \
        BARRIER();                                                              \
        if ((kt) + 1 < NT) { WAITV4(); } else { WAITV0(); }                     \
        __builtin_amdgcn_s_setprio(1); mfmaQ(0, 1); __builtin_amdgcn_s_setprio(0); \
        BARRIER();                                                              \
        /* p3 */                                                                \
        _Pragma("unroll") for (int i = 0; i < 4; ++i)                           \
            _Pragma("unroll") for (int kk = 0; kk < 2; ++kk)                    \
                a[i][kk] = readA(par, 4 + i, kk);                                \
        MEMFENCE();                                                             \
        BARRIER();                                                              \
        LGKM0();                                                                \
        __builtin_amdgcn_s_setprio(1); mfmaQ(1, 0); __builtin_amdgcn_s_setprio(0); \
        BARRIER();                                                              \
        /* p4: issue b01(t+1) FIRST, then vmcnt(4) drains exactly sA(t+1) */    \
        if ((kt) + 1 < NT) {                                                    \
            _Pragma("unroll") for (int nf = 0; nf < 2; ++nf)                    \
                _Pragma("unroll") for (int kk = 0; kk < 2; ++kk)                \
                    b[nf][kk] = loadB(nf, kk, (kt) + 1);                         \
            MEMFENCE();                                                         \
            WAITV4();                                                           \
        } else { WAITV0(); }                                                    \
        BARRIER();                                                              \
        __builtin_amdgcn_s_setprio(1); mfmaQ(1, 1); __builtin_amdgcn_s_setprio(0); \
        BARRIER();                                                              \
    }

#pragma unroll 1
    for (int kt = 0; kt < NT; kt += 2) {
        KTILE(kt, 0);
        KTILE(kt + 1, 1);
    }
#undef KTILE

    // --- epilogue: C = acc + (b + lora_bias); NT stores ---
#pragma unroll
    for (int nf = 0; nf < 4; ++nf) {
        const int gc = n0 + wc * 64 + nf * 16 + (lane & 15);
        const float bv = bvec[gc] + lbvec[gc];
#pragma unroll
        for (int mf = 0; mf < 8; ++mf) {
            const int gr0 = m0 + wr * 128 + mf * 16 + (lane >> 4) * 4;
            f32x4 v = acc[mf][nf];
#pragma unroll
            for (int j = 0; j < 4; ++j)
                __builtin_nontemporal_store(v[j] + bv, &C[(size_t)(gr0 + j) * N_DIM + gc]);
        }
    }
}

// --- Fallback: naive fp32 (only if ws too small) ----------------------------
__global__ __launch_bounds__(256) void naive_kernel(
    const float* __restrict__ x, const float* __restrict__ W,
    const float* __restrict__ b, const float* __restrict__ lA,
    const float* __restrict__ lB, const float* __restrict__ lb,
    float* __restrict__ out) {
    __shared__ float xs[K_DIM];
    __shared__ float ts[16];
    const int m = blockIdx.x;
    const int tid = threadIdx.x;
    for (int k = tid; k < K_DIM; k += 256) xs[k] = x[(size_t)m * K_DIM + k];
    if (tid < 16) ts[tid] = 0.f;
    __syncthreads();
    float part[16] = {};
    for (int k = tid * 16; k < tid * 16 + 16; ++k) {
        float xv = xs[k];
#pragma unroll
        for (int r = 0; r < 16; ++r) part[r] += xv * lA[(size_t)r * K_DIM + k];
    }
#pragma unroll
    for (int r = 0; r < 16; ++r) atomicAdd(&ts[r], part[r]);
    __syncthreads();
    const int n = blockIdx.y * 256 + tid;
    float acc = b[n] + lb[n];
#pragma unroll
    for (int r = 0; r < 16; ++r) acc += ts[r] * lB[(size_t)n * 16 + r];
    const float* wrow = W + (size_t)n * K_DIM;
    for (int k = 0; k < K_DIM; ++k) acc += xs[k] * wrow[k];
    out[(size_t)m * N_DIM + n] = acc;
}

// ---------------------------------------------------------------------------
extern "C" void kernel_launch(void* const* d_in, const int* in_sizes, int n_in,
                              void* d_out, int out_size, void* d_ws, size_t ws_size,
                              hipStream_t stream) {
    const float* x  = (const float*)d_in[0];
    const float* W  = (const float*)d_in[1];
    const float* b  = (const float*)d_in[2];
    const float* lA = (const float*)d_in[3];
    const float* lB = (const float*)d_in[4];
    const float* lb = (const float*)d_in[5];
    float* out = (float*)d_out;

    const size_t xb_bytes = (size_t)M_DIM * K_DIM * 2;  // 64 MiB
    const size_t wb_bytes = (size_t)N_DIM * K_DIM * 2;  // 32 MiB

    if (ws_size >= xb_bytes + wb_bytes) {
        unsigned short* xb = (unsigned short*)d_ws;
        unsigned short* wb = (unsigned short*)((char*)d_ws + xb_bytes);

        conv_xw_kernel<<<CONVX_BLOCKS + N_DIM / 4, 512, 0, stream>>>(
            x, xb, W, lA, lB, wb);

        gemm_kernel<<<(M_DIM / 256) * (N_DIM / 256), 512, 0, stream>>>(xb, wb, b, lb, out);
    } else {
        dim3 grid(M_DIM, N_DIM / 256);
        naive_kernel<<<grid, 256, 0, stream>>>(x, W, b, lA, lB, lb, out);
    }
}

// Round 21
// 305.299 us; speedup vs baseline: 1.5330x; 1.5330x over previous
//
#include <hip/hip_runtime.h>
#include <hip/hip_bf16.h>
#include <stdint.h>

// ---------------------------------------------------------------------------
// LoRALinear: y = x @ (W + B@A)^T + (b + lora_bias)
// M=8192, N=4096, K=4096.
// R21 = champion restored (R16/R18). gemm = R13 schedule: best of 15
// variants (260-265us / 1041 TF / MfmaUtil 46 / conflicts 0 / no spill).
// Exploration ledger CLOSED:
//  - tiles {128^2(R17), 256^2, 512x256(R4)}, waves {4(R11),8}, blk/CU {1,2}
//  - shapes {16x16x32, 32x32x16(R12: swizzle conflicts)}
//  - barriers/KT {1(R15),2(R9),8(R13)}; drain styles (R10,R13,R19-fence)
//  - staging {bunched, staggered(R13), all-at-top(R15), B-direct(R20: 426us,
//    uncoalesced 16-line/wave B loads on vmcnt critical path)}
//  - NT stores (R8 neutral), XCD mappings (R7: +8%)
// Serial ledger: wall/KT = MFMA(2483) + LDS(~2300) + sync(~700). The two
// pipes would not overlap under any HIP-level barrier/waitcnt arrangement.
// ---------------------------------------------------------------------------

#define M_DIM 8192
#define N_DIM 4096
#define K_DIM 4096
#define NT    (K_DIM / 64)   // 64 K-tiles

typedef __attribute__((ext_vector_type(8))) short bf16x8;
typedef __attribute__((ext_vector_type(4))) float f32x4;

#define BARRIER() __builtin_amdgcn_s_barrier()
#define WAITV8() asm volatile("s_waitcnt vmcnt(8)" ::: "memory")
#define WAITV4() asm volatile("s_waitcnt vmcnt(4)" ::: "memory")
#define WAITV0() asm volatile("s_waitcnt vmcnt(0)" ::: "memory")
#define LGKM0()  asm volatile("s_waitcnt lgkmcnt(0)" ::: "memory")
#define LGKM8()  asm volatile("s_waitcnt lgkmcnt(8)" ::: "memory")

static __device__ __forceinline__ unsigned short f2bf(float f) {
    unsigned int u = __builtin_bit_cast(unsigned int, f);
    unsigned int r = (u + 0x7fffu + ((u >> 16) & 1u)) >> 16;
    return (unsigned short)r;
}

// --- merged pre-pass: blocks [0,8192) convert x -> bf16 (8 elems/thread);
//     blocks [8192,9216) compute bf16(W + B@A), 4 rows/block. -----------------
#define CONVX_BLOCKS 8192
__global__ __launch_bounds__(512) void conv_xw_kernel(
    const float* __restrict__ x, unsigned short* __restrict__ xb,
    const float* __restrict__ W, const float* __restrict__ lA,
    const float* __restrict__ lB, unsigned short* __restrict__ Wb) {
    const int bid = blockIdx.x;
    if (bid < CONVX_BLOCKS) {
        size_t i = ((size_t)bid * 512 + threadIdx.x) * 8;
        float4 a = *(const float4*)(x + i);
        float4 c = *(const float4*)(x + i + 4);
        union { unsigned short us[8]; uint4 v; } u;
        u.us[0] = f2bf(a.x); u.us[1] = f2bf(a.y); u.us[2] = f2bf(a.z); u.us[3] = f2bf(a.w);
        u.us[4] = f2bf(c.x); u.us[5] = f2bf(c.y); u.us[6] = f2bf(c.z); u.us[7] = f2bf(c.w);
        *(uint4*)(xb + i) = u.v;
        return;
    }
    const int nb = (bid - CONVX_BLOCKS) * 4;
    const int k0 = threadIdx.x * 8;       // 512 thr * 8 = 4096

    float acc[4][8];
#pragma unroll
    for (int r = 0; r < 4; ++r) {
        const float4* w4 = (const float4*)(W + (size_t)(nb + r) * K_DIM + k0);
        float4 v0 = w4[0], v1 = w4[1];
        acc[r][0] = v0.x; acc[r][1] = v0.y; acc[r][2] = v0.z; acc[r][3] = v0.w;
        acc[r][4] = v1.x; acc[r][5] = v1.y; acc[r][6] = v1.z; acc[r][7] = v1.w;
    }
    float brs[4][16];
#pragma unroll
    for (int r = 0; r < 4; ++r)
#pragma unroll
        for (int t = 0; t < 16; ++t) brs[r][t] = lB[(size_t)(nb + r) * 16 + t];

#pragma unroll
    for (int t = 0; t < 16; ++t) {
        const float4* a4 = (const float4*)(lA + (size_t)t * K_DIM + k0);
        float4 v0 = a4[0], v1 = a4[1];
        float av[8] = {v0.x, v0.y, v0.z, v0.w, v1.x, v1.y, v1.z, v1.w};
#pragma unroll
        for (int r = 0; r < 4; ++r)
#pragma unroll
            for (int j = 0; j < 8; ++j) acc[r][j] += brs[r][t] * av[j];
    }
#pragma unroll
    for (int r = 0; r < 4; ++r) {
        union { unsigned short us[8]; uint4 v; } u;
#pragma unroll
        for (int j = 0; j < 8; ++j) u.us[j] = f2bf(acc[r][j]);
        *(uint4*)(Wb + (size_t)(nb + r) * K_DIM + k0) = u.v;
    }
}

// --- gemm: 256x256 tile, BK=64, 8 waves, m201 8-phase staggered staging -----
// (R13 champion, byte-identical)
__global__ __launch_bounds__(512, 2) void gemm_kernel(
    const unsigned short* __restrict__ A,   // [8192][4096] bf16
    const unsigned short* __restrict__ B,   // [4096][4096] bf16 (W')
    const float* __restrict__ bvec, const float* __restrict__ lbvec,
    float* __restrict__ C) {
    const int tid = threadIdx.x;
    const int lane = tid & 63;
    const int wid = tid >> 6;        // 0..7
    const int wr = wid >> 2;         // 0..1  M-half (128 rows)
    const int wc = wid & 3;          // 0..3  N-quarter (64 cols)

    // XCD-column-resident mapping (R7)
    const int bid = blockIdx.x;
    const int ntile = (bid & 7) * 2 + ((bid >> 3) & 1);  // 0..15
    const int mtile = bid >> 4;                          // 0..31
    const int m0 = mtile * 256, n0 = ntile * 256;

    __shared__ __align__(16) unsigned short ldsA[2 * 2 * 128 * 64];  // 64 KiB
    __shared__ __align__(16) unsigned short ldsB[2 * 2 * 128 * 64];  // 64 KiB

    // --- staging: linear LDS dest, inverse-swizzled global src (T2) ---
    const int lr8 = lane >> 3;             // 0..7
    const int cch = (lane & 7) ^ lr8;      // swizzled 16B-chunk index
    const unsigned short* aSb = A + (size_t)(m0 + lr8) * K_DIM + cch * 8;
    const unsigned short* bSb = B + (size_t)(n0 + lr8) * K_DIM + cch * 8;

    auto stageA = [&](int par_, int h, int kt) {   // one half-tile = 2 loads
#pragma unroll
        for (int s = 0; s < 2; ++s) {
            const int j = wid * 2 + s;
            const unsigned short* g = aSb + (size_t)(h * 128 + j * 8) * K_DIM + kt * 64;
            __builtin_amdgcn_global_load_lds(
                (const __attribute__((address_space(1))) void*)g,
                (__attribute__((address_space(3))) void*)(ldsA + (par_ * 2 + h) * 8192 + j * 512),
                16, 0, 0);
        }
    };
    auto stageB = [&](int par_, int h, int kt) {
#pragma unroll
        for (int s = 0; s < 2; ++s) {
            const int j = wid * 2 + s;
            const unsigned short* g = bSb + (size_t)(h * 128 + j * 8) * K_DIM + kt * 64;
            __builtin_amdgcn_global_load_lds(
                (const __attribute__((address_space(1))) void*)g,
                (__attribute__((address_space(3))) void*)(ldsB + (par_ * 2 + h) * 8192 + j * 512),
                16, 0, 0);
        }
    };

    // --- read side (T2 swizzle) ---
    const int rowByte = (lane & 15) * 128;
    const int swz = (lane & 7) << 4;
    const int kc0 = (0 * 64 + (lane >> 4) * 16) ^ swz;
    const int kc1 = (1 * 64 + (lane >> 4) * 16) ^ swz;
    const int baseBoff = (wc & 1) * 4096;

    auto readA = [&](int par_, int mf, int kk) -> bf16x8 {
        const char* p = (const char*)(ldsA + (par_ * 2 + wr) * 8192 + mf * 1024) +
                        rowByte + (kk ? kc1 : kc0);
        return *(const bf16x8*)p;
    };
    auto readB = [&](int par_, int nf, int kk) -> bf16x8 {
        const char* p = (const char*)(ldsB + (par_ * 2 + (wc >> 1)) * 8192 + baseBoff + nf * 1024) +
                        rowByte + (kk ? kc1 : kc0);
        return *(const bf16x8*)p;
    };

    f32x4 acc[8][4] = {};
    bf16x8 a[4][2], b[4][2];

    auto mfmaQ = [&](int qm, int qn) {   // 16 MFMA: 4 mf x 2 nf x 2 kk
#pragma unroll
        for (int i = 0; i < 4; ++i)
#pragma unroll
            for (int jn = 0; jn < 2; ++jn)
#pragma unroll
                for (int kk = 0; kk < 2; ++kk)
                    acc[qm * 4 + i][qn * 2 + jn] = __builtin_amdgcn_mfma_f32_16x16x32_bf16(
                        a[i][kk], b[qn * 2 + jn][kk], acc[qm * 4 + i][qn * 2 + jn], 0, 0, 0);
    };

    // --- prologue: issue in ledger order A(0),B(0),A(1),B(1); drain t0 ---
    stageA(0, 0, 0); stageA(0, 1, 0); stageB(0, 0, 0); stageB(0, 1, 0);
    stageA(1, 0, 1); stageA(1, 1, 1); stageB(1, 0, 1); stageB(1, 1, 1);
    WAITV8();               // t0's 8 drained; t1's 8 in flight
    BARRIER();              // publish t0

    // Per K-tile: p1: 12 reads + stageA(t+1,h0)   p2: 4 reads + stageA(t+1,h1)
    //             p3: 8 reads + stageB(t+2,h0)    p4: stageB(t+2,h1) + vmcnt(4)
#define KTILE(kt, par)                                                          \
    {                                                                           \
        /* p1 */                                                                \
        _Pragma("unroll") for (int i = 0; i < 4; ++i)                           \
            _Pragma("unroll") for (int kk = 0; kk < 2; ++kk)                    \
                a[i][kk] = readA(par, i, kk);                                    \
        _Pragma("unroll") for (int nf = 0; nf < 2; ++nf)                        \
            _Pragma("unroll") for (int kk = 0; kk < 2; ++kk)                    \
                b[nf][kk] = readB(par, nf, kk);                                  \
        if ((kt) >= 1 && (kt) + 1 < NT) stageA((par) ^ 1, 0, (kt) + 1);         \
        LGKM8();                                                                \
        BARRIER();                                                              \
        LGKM0();                                                                \
        __builtin_amdgcn_s_setprio(1); mfmaQ(0, 0); __builtin_amdgcn_s_setprio(0); \
        BARRIER();                                                              \
        /* p2 */                                                                \
        _Pragma("unroll") for (int nf = 2; nf < 4; ++nf)                        \
            _Pragma("unroll") for (int kk = 0; kk < 2; ++kk)                    \
                b[nf][kk] = readB(par, nf, kk);                                  \
        if ((kt) >= 1 && (kt) + 1 < NT) stageA((par) ^ 1, 1, (kt) + 1);         \
        BARRIER();                                                              \
        LGKM0();                                                                \
        __builtin_amdgcn_s_setprio(1); mfmaQ(0, 1); __builtin_amdgcn_s_setprio(0); \
        BARRIER();                                                              \
        /* p3 (B(par) last read at p2 -> safe to overwrite for t+2) */          \
        _Pragma("unroll") for (int i = 0; i < 4; ++i)                           \
            _Pragma("unroll") for (int kk = 0; kk < 2; ++kk)                    \
                a[i][kk] = readA(par, 4 + i, kk);                                \
        if ((kt) + 2 < NT) stageB(par, 0, (kt) + 2);                            \
        BARRIER();                                                              \
        LGKM0();                                                                \
        __builtin_amdgcn_s_setprio(1); mfmaQ(1, 0); __builtin_amdgcn_s_setprio(0); \
        BARRIER();                                                              \
        /* p4: ledger = 12 outstanding; vmcnt(4) drains {A(t+1),B(t+1)} */      \
        if ((kt) + 2 < NT) { stageB(par, 1, (kt) + 2); WAITV4(); }              \
        else { WAITV0(); }                                                      \
        BARRIER();                                                              \
        __builtin_amdgcn_s_setprio(1); mfmaQ(1, 1); __builtin_amdgcn_s_setprio(0); \
        BARRIER();                                                              \
    }

#pragma unroll 1
    for (int kt = 0; kt < NT; kt += 2) {
        KTILE(kt, 0);
        KTILE(kt + 1, 1);
    }
#undef KTILE

    // --- epilogue: C = acc + (b + lora_bias); NT stores ---
#pragma unroll
    for (int nf = 0; nf < 4; ++nf) {
        const int gc = n0 + wc * 64 + nf * 16 + (lane & 15);
        const float bv = bvec[gc] + lbvec[gc];
#pragma unroll
        for (int mf = 0; mf < 8; ++mf) {
            const int gr0 = m0 + wr * 128 + mf * 16 + (lane >> 4) * 4;
            f32x4 v = acc[mf][nf];
#pragma unroll
            for (int j = 0; j < 4; ++j)
                __builtin_nontemporal_store(v[j] + bv, &C[(size_t)(gr0 + j) * N_DIM + gc]);
        }
    }
}

// --- Fallback: naive fp32 (only if ws too small) ----------------------------
__global__ __launch_bounds__(256) void naive_kernel(
    const float* __restrict__ x, const float* __restrict__ W,
    const float* __restrict__ b, const float* __restrict__ lA,
    const float* __restrict__ lB, const float* __restrict__ lb,
    float* __restrict__ out) {
    __shared__ float xs[K_DIM];
    __shared__ float ts[16];
    const int m = blockIdx.x;
    const int tid = threadIdx.x;
    for (int k = tid; k < K_DIM; k += 256) xs[k] = x[(size_t)m * K_DIM + k];
    if (tid < 16) ts[tid] = 0.f;
    __syncthreads();
    float part[16] = {};
    for (int k = tid * 16; k < tid * 16 + 16; ++k) {
        float xv = xs[k];
#pragma unroll
        for (int r = 0; r < 16; ++r) part[r] += xv * lA[(size_t)r * K_DIM + k];
    }
#pragma unroll
    for (int r = 0; r < 16; ++r) atomicAdd(&ts[r], part[r]);
    __syncthreads();
    const int n = blockIdx.y * 256 + tid;
    float acc = b[n] + lb[n];
#pragma unroll
    for (int r = 0; r < 16; ++r) acc += ts[r] * lB[(size_t)n * 16 + r];
    const float* wrow = W + (size_t)n * K_DIM;
    for (int k = 0; k < K_DIM; ++k) acc += xs[k] * wrow[k];
    out[(size_t)m * N_DIM + n] = acc;
}

// ---------------------------------------------------------------------------
extern "C" void kernel_launch(void* const* d_in, const int* in_sizes, int n_in,
                              void* d_out, int out_size, void* d_ws, size_t ws_size,
                              hipStream_t stream) {
    const float* x  = (const float*)d_in[0];
    const float* W  = (const float*)d_in[1];
    const float* b  = (const float*)d_in[2];
    const float* lA = (const float*)d_in[3];
    const float* lB = (const float*)d_in[4];
    const float* lb = (const float*)d_in[5];
    float* out = (float*)d_out;

    const size_t xb_bytes = (size_t)M_DIM * K_DIM * 2;  // 64 MiB
    const size_t wb_bytes = (size_t)N_DIM * K_DIM * 2;  // 32 MiB

    if (ws_size >= xb_bytes + wb_bytes) {
        unsigned short* xb = (unsigned short*)d_ws;
        unsigned short* wb = (unsigned short*)((char*)d_ws + xb_bytes);

        conv_xw_kernel<<<CONVX_BLOCKS + N_DIM / 4, 512, 0, stream>>>(
            x, xb, W, lA, lB, wb);

        gemm_kernel<<<(M_DIM / 256) * (N_DIM / 256), 512, 0, stream>>>(xb, wb, b, lb, out);
    } else {
        dim3 grid(M_DIM, N_DIM / 256);
        naive_kernel<<<grid, 256, 0, stream>>>(x, W, b, lA, lB, lb, out);
    }
}